// Round 5
// baseline (305.333 us; speedup 1.0000x reference)
//
#include <hip/hip_runtime.h>
#include <hip/hip_bf16.h>

#define D    128   // EMBED_DIM
#define D2   256   // 2*EMBED_DIM
#define XS   264   // padded X tile row (ushorts)
#define H1P  272   // padded h1 tile row (ushorts)
#define LMAX 128   // max items handled per row (4 groups of 32)
#define MAXSLOT 64 // 16 rows * 4 groups

typedef short bf16x8 __attribute__((ext_vector_type(8)));
typedef float f32x4  __attribute__((ext_vector_type(4)));

__device__ __forceinline__ float bf2f(unsigned short u) {
    return __uint_as_float(((unsigned int)u) << 16);
}
__device__ __forceinline__ float bflo(unsigned int p) { return __uint_as_float(p << 16); }
__device__ __forceinline__ float bfhi(unsigned int p) { return __uint_as_float(p & 0xffff0000u); }
__device__ __forceinline__ unsigned short f2bf(float f) {
    __hip_bfloat16 h = __float2bfloat16(f);
    return *(unsigned short*)&h;
}

template<bool BF>
__device__ __forceinline__ float ld1(const void* p, size_t i) {
    if constexpr (BF) return bf2f(((const unsigned short*)p)[i]);
    else              return ((const float*)p)[i];
}

template<bool BF>
__device__ __forceinline__ void load8f(const void* p, size_t elem_off, float* r) {
    if constexpr (BF) {
        uint4 v = *(const uint4*)((const unsigned short*)p + elem_off);
        r[0]=bflo(v.x); r[1]=bfhi(v.x); r[2]=bflo(v.y); r[3]=bfhi(v.y);
        r[4]=bflo(v.z); r[5]=bfhi(v.z); r[6]=bflo(v.w); r[7]=bfhi(v.w);
    } else {
        const float4* q = (const float4*)((const float*)p + elem_off);
        float4 a = q[0], b = q[1];
        r[0]=a.x; r[1]=a.y; r[2]=a.z; r[3]=a.w;
        r[4]=b.x; r[5]=b.y; r[6]=b.z; r[7]=b.w;
    }
}

__device__ __forceinline__ void unpack8(uint4 v, float* r) {
    r[0]=bflo(v.x); r[1]=bfhi(v.x); r[2]=bflo(v.y); r[3]=bfhi(v.y);
    r[4]=bflo(v.z); r[5]=bfhi(v.z); r[6]=bflo(v.w); r[7]=bfhi(v.w);
}

__device__ __forceinline__ void store8bf(unsigned short* p, const float* r) {
    union { unsigned short u[8]; uint4 v; } pk;
    #pragma unroll
    for (int k = 0; k < 8; ++k) pk.u[k] = f2bf(r[k]);
    *(uint4*)p = pk.v;
}

__device__ __forceinline__ bool read_mask(const void* mask, int mmode, size_t i) {
    if (mmode == 0) return ((const int*)mask)[i] != 0;
    if (mmode == 1) return ((const unsigned char*)mask)[i] != 0;
    return ((const unsigned short*)mask)[i] != 0;
}

// Wave-local dtype probe (no LDS, no barrier): identical count in every wave.
__device__ __forceinline__ bool probe_is_bf16(const unsigned int* probe) {
    const int lane = threadIdx.x & 63;
    int cnt = 0;
    #pragma unroll
    for (int i = 0; i < 4; ++i) {
        unsigned int e = (probe[lane + 64 * i] >> 7) & 0xffu;
        cnt += (e >= 90 && e < 130) ? 1 : 0;
    }
    #pragma unroll
    for (int o = 32; o; o >>= 1) cnt += __shfl_xor(cnt, o);
    return cnt >= 128;
}

template<bool BF>
__device__ __forceinline__ bf16x8 load_w8(const void* W, size_t off) {
    if constexpr (BF) {
        return *(const bf16x8*)((const unsigned short*)W + off);
    } else {
        const float* p = (const float*)W + off;
        float4 a = *(const float4*)p;
        float4 b = *(const float4*)(p + 4);
        bf16x8 r;
        r[0] = (short)f2bf(a.x); r[1] = (short)f2bf(a.y);
        r[2] = (short)f2bf(a.z); r[3] = (short)f2bf(a.w);
        r[4] = (short)f2bf(b.x); r[5] = (short)f2bf(b.y);
        r[6] = (short)f2bf(b.z); r[7] = (short)f2bf(b.w);
        return r;
    }
}

// ---------------------------------------------------------------------------
// Fused kernel v2: ONE BLOCK (8 waves, 512 thr) per 16 rows.
// Phase 1 (balanced): block's (row, 32-item-group) slots are compacted via a
// prefix-sum; wave w processes slots w, w+8, ... (balance +-1 group), writing
// per-slot partials (esum + 128-dim acc) to LDS.  No barriers in the loop.
// Phase 2: per-row combine (slots contiguous), x_s tile, then MFMA MLP.
// ---------------------------------------------------------------------------
template<bool BF>
__device__ __forceinline__ void fused_body(
    const int* __restrict__ x_u, const int* __restrict__ x_b,
    const int* __restrict__ items, const void* __restrict__ mask, int mmode,
    const void* __restrict__ emb_u, const void* __restrict__ emb_i,
    const void* __restrict__ emb_b, const void* __restrict__ Aw,
    const void* __restrict__ fc1_w, const void* __restrict__ fc1_b,
    const void* __restrict__ fc2_w, const void* __restrict__ fc2_b,
    const void* __restrict__ out_w, const void* __restrict__ out_b,
    void* __restrict__ out, int L,
    int* it_s, float (*hu_s)[D], float (*part)[132],
    int* len_s, int* pfx_s, unsigned char* srow_s, unsigned char* sgrp_s,
    unsigned short* x_s, unsigned short* h1_s, float (*po_s)[16])
{
    const int tid  = threadIdx.x;
    const int wave = tid >> 6;          // 0..7
    const int lane = tid & 63;
    const int g    = lane >> 4;
    const int m16  = lane & 15;
    const int l16  = lane & 15;
    const int quad = lane >> 4;
    const int mt   = blockIdx.x * 16;

    // ================= setup: stage items, lens, h_u (rows wave, wave+8) ====
    #pragma unroll
    for (int rr = 0; rr < 2; ++rr) {
        const int r = wave + rr * 8;
        const int b = mt + r;
        const int  c0 = (lane < L) ? lane : 0;
        int  i0 = items[(size_t)b * L + c0];
        bool v0 = (lane < L) && read_mask(mask, mmode, (size_t)b * L + c0);
        int  i1 = 0;
        bool v1 = false;
        if (64 + lane < L) {
            i1 = items[(size_t)b * L + 64 + lane];
            v1 = read_mask(mask, mmode, (size_t)b * L + 64 + lane);
        }
        if (lane < L)       it_s[r * LMAX + lane]      = i0;
        if (64 + lane < L && 64 + lane < LMAX) it_s[r * LMAX + 64 + lane] = i1;
        int len = __popcll(__ballot(v0)) + __popcll(__ballot(v1));
        if (len > LMAX) len = LMAX;
        if (lane == 0) len_s[r] = len;

        const int xu = x_u[b];
        if (g == 0) {
            float r8[8];
            load8f<BF>(emb_u, (size_t)xu * D + m16 * 8, r8);
            #pragma unroll
            for (int k = 0; k < 8; ++k) hu_s[r][m16 * 8 + k] = r8[k];
            if constexpr (BF) {   // bit-exact pass-through of h_u
                uint4 raw = *(const uint4*)((const unsigned short*)emb_u
                                            + (size_t)xu * D + m16 * 8);
                *(uint4*)(x_s + (size_t)r * XS + m16 * 8) = raw;
            } else {
                store8bf(x_s + (size_t)r * XS + m16 * 8, r8);
            }
        }
    }
    __syncthreads();

    // ================= slot table (prefix-sum over groups) ==================
    if (tid < 17) {
        int s = 0;
        for (int i = 0; i < tid; ++i) {
            const int gi = (len_s[i] + 31) >> 5;
            s += (gi < 4) ? gi : 4;
        }
        pfx_s[tid] = s;
    }
    __syncthreads();
    const int nslots = pfx_s[16];
    if (tid < nslots) {
        int r = 0;
        while (pfx_s[r + 1] <= tid) ++r;
        srow_s[tid] = (unsigned char)r;
        sgrp_s[tid] = (unsigned char)(tid - pfx_s[r]);
    }
    __syncthreads();

    // ================= balanced slot processing =============================
    for (int k = wave; k < nslots; k += 8) {
        const int row = srow_s[k];
        const int grp = sgrp_s[k];
        const int len = len_s[row];
        const int* itr = &it_s[row * LMAX];

        float hu8[8];
        #pragma unroll
        for (int j = 0; j < 8; ++j) hu8[j] = hu_s[row][m16 * 8 + j];

        float esum = 0.f;
        float acc8[8];
        #pragma unroll
        for (int j = 0; j < 8; ++j) acc8[j] = 0.f;

        if constexpr (BF) {
            const unsigned short* AW = (const unsigned short*)Aw;
            const unsigned short* EI = (const unsigned short*)emb_i;
            int idq[8];
            #pragma unroll
            for (int q = 0; q < 8; ++q) {
                const int idx = grp * 32 + 4 * q + g;
                idq[q] = itr[(idx < len) ? idx : 0];
            }
            uint4 ab[8], vb[8];
            #pragma unroll
            for (int q = 0; q < 8; ++q) {          // burst: 16 loads in flight
                ab[q] = *(const uint4*)(AW + (size_t)idq[q] * D + m16 * 8);
                vb[q] = *(const uint4*)(EI + (size_t)idq[q] * D + m16 * 8);
            }
            #pragma unroll
            for (int q = 0; q < 8; ++q) {          // consume
                float af[8];
                unpack8(ab[q], af);
                float s = 0.f;
                #pragma unroll
                for (int j = 0; j < 8; ++j) s += hu8[j] * af[j];
                s += __shfl_xor(s, 1); s += __shfl_xor(s, 2);
                s += __shfl_xor(s, 4); s += __shfl_xor(s, 8);
                const int idx = grp * 32 + 4 * q + g;
                const float e = (idx < len) ? __expf(s) : 0.f;
                esum += e;
                float vf[8];
                unpack8(vb[q], vf);
                #pragma unroll
                for (int j = 0; j < 8; ++j) acc8[j] += e * vf[j];
            }
        } else {
            float a0[8], u0[8], a1[8], u1[8];
            auto fetchf = [&](int q, float* a, float* v) {
                const int idx = grp * 32 + 4 * q + g;
                const int id = itr[(idx < len) ? idx : 0];
                load8f<false>(Aw,    (size_t)id * D + m16 * 8, a);
                load8f<false>(emb_i, (size_t)id * D + m16 * 8, v);
            };
            fetchf(0, a0, u0);
            fetchf(1, a1, u1);
            for (int q = 0; q < 8; ++q) {
                float ca[8], cv[8];
                #pragma unroll
                for (int j = 0; j < 8; ++j) { ca[j] = a0[j]; cv[j] = u0[j]; }
                #pragma unroll
                for (int j = 0; j < 8; ++j) { a0[j] = a1[j]; u0[j] = u1[j]; }
                if (q + 2 < 8) fetchf(q + 2, a1, u1);
                float s = 0.f;
                #pragma unroll
                for (int j = 0; j < 8; ++j) s += hu8[j] * ca[j];
                s += __shfl_xor(s, 1); s += __shfl_xor(s, 2);
                s += __shfl_xor(s, 4); s += __shfl_xor(s, 8);
                const int idx = grp * 32 + 4 * q + g;
                const float e = (idx < len) ? __expf(s) : 0.f;
                esum += e;
                #pragma unroll
                for (int j = 0; j < 8; ++j) acc8[j] += e * cv[j];
            }
        }

        // combine the 4 subgroups within the wave; write per-slot partial
        esum += __shfl_xor(esum, 16);
        esum += __shfl_xor(esum, 32);
        #pragma unroll
        for (int j = 0; j < 8; ++j) {
            acc8[j] += __shfl_xor(acc8[j], 16);
            acc8[j] += __shfl_xor(acc8[j], 32);
        }
        if (g == 0) {
            #pragma unroll
            for (int j = 0; j < 8; ++j) part[k][m16 * 8 + j] = acc8[j];
            if (m16 == 0) part[k][128] = esum;
        }
    }
    __syncthreads();

    // ================= per-row combine + x_s second half ====================
    if (g == 0) {
        #pragma unroll
        for (int rr = 0; rr < 2; ++rr) {
            const int r = wave + rr * 8;
            const int b = mt + r;
            float at[8];
            #pragma unroll
            for (int j = 0; j < 8; ++j) at[j] = 0.f;
            float es = 0.f;
            const int k0 = pfx_s[r], k1 = pfx_s[r + 1];
            for (int k = k0; k < k1; ++k) {
                #pragma unroll
                for (int j = 0; j < 8; ++j) at[j] += part[k][m16 * 8 + j];
                es += part[k][128];
            }
            const float inv = (es > 0.f) ? 1.f / es : 0.f;
            const int xb = x_b[b];
            float rb2[8], outv[8];
            load8f<BF>(emb_b, (size_t)xb * D + m16 * 8, rb2);
            #pragma unroll
            for (int j = 0; j < 8; ++j) outv[j] = rb2[j] + at[j] * inv;
            store8bf(x_s + (size_t)r * XS + D + m16 * 8, outv);
        }
    }
    __syncthreads();

    // ================= MLP stage 1: X @ fc1_w^T =============================
    bf16x8 afrag[8];
    #pragma unroll
    for (int kc = 0; kc < 8; ++kc)
        afrag[kc] = *(const bf16x8*)&x_s[l16 * XS + quad * 8 + kc * 32];

    #pragma unroll
    for (int jj = 0; jj < 2; ++jj) {
        const int jt = wave * 2 + jj;
        const size_t bbase = (size_t)(jt * 16 + l16) * D2 + quad * 8;
        f32x4 acc = {0.f, 0.f, 0.f, 0.f};
        #pragma unroll
        for (int kc = 0; kc < 8; ++kc) {
            bf16x8 bfrag = load_w8<BF>(fc1_w, bbase + kc * 32);
            acc = __builtin_amdgcn_mfma_f32_16x16x32_bf16(afrag[kc], bfrag, acc, 0, 0, 0);
        }
        const int j  = jt * 16 + l16;
        const float bj = ld1<BF>(fc1_b, j);
        #pragma unroll
        for (int r = 0; r < 4; ++r) {
            float v = acc[r] + bj;
            v = v > 0.f ? v : 0.01f * v;
            h1_s[(quad * 4 + r) * H1P + j] = f2bf(v);
        }
    }
    __syncthreads();

    // ================= MLP stage 2 + fused out-dot ==========================
    bf16x8 afrag2[8];
    #pragma unroll
    for (int kc = 0; kc < 8; ++kc)
        afrag2[kc] = *(const bf16x8*)&h1_s[l16 * H1P + quad * 8 + kc * 32];

    float po[4] = {0.f, 0.f, 0.f, 0.f};
    #pragma unroll
    for (int jj = 0; jj < 2; ++jj) {
        const int jt = wave * 2 + jj;
        const size_t bbase = (size_t)(jt * 16 + l16) * D2 + quad * 8;
        f32x4 acc = {0.f, 0.f, 0.f, 0.f};
        #pragma unroll
        for (int kc = 0; kc < 8; ++kc) {
            bf16x8 bfrag = load_w8<BF>(fc2_w, bbase + kc * 32);
            acc = __builtin_amdgcn_mfma_f32_16x16x32_bf16(afrag2[kc], bfrag, acc, 0, 0, 0);
        }
        const int j  = jt * 16 + l16;
        const float bj = ld1<BF>(fc2_b, j);
        const float wj = ld1<BF>(out_w, j);
        #pragma unroll
        for (int r = 0; r < 4; ++r) {
            float v = acc[r] + bj;
            v = v > 0.f ? v : 0.01f * v;
            po[r] += v * wj;
        }
    }
    #pragma unroll
    for (int r = 0; r < 4; ++r) {
        #pragma unroll
        for (int o = 1; o < 16; o <<= 1) po[r] += __shfl_xor(po[r], o);
    }
    if (l16 == 0) {
        #pragma unroll
        for (int r = 0; r < 4; ++r) po_s[wave][quad * 4 + r] = po[r];
    }
    __syncthreads();

    if (tid < 16) {
        float v = ld1<BF>(out_b, 0);
        #pragma unroll
        for (int w = 0; w < 8; ++w) v += po_s[w][tid];
        if constexpr (BF) ((unsigned short*)out)[mt + tid] = f2bf(v);
        else              ((float*)out)[mt + tid] = v;
    }
}

__global__ __launch_bounds__(512, 4) void fused_kernel(
    const int* x_u, const int* x_b, const int* items, const void* mask,
    const void* emb_u, const void* emb_i, const void* emb_b, const void* A,
    const void* fc1_w, const void* fc1_b, const void* fc2_w, const void* fc2_b,
    const void* out_w, const void* out_b, void* out, int L)
{
    __shared__ int   it_s[16 * LMAX];          // 8 KB
    __shared__ float hu_s[16][D];              // 8 KB
    __shared__ float part[MAXSLOT][132];       // 33.8 KB
    __shared__ int   len_s[16];
    __shared__ int   pfx_s[17];
    __shared__ unsigned char srow_s[MAXSLOT];
    __shared__ unsigned char sgrp_s[MAXSLOT];
    __shared__ unsigned short x_s[16 * XS];    // 8.4 KB
    __shared__ unsigned short h1_s[16 * H1P];  // 8.7 KB
    __shared__ float po_s[8][16];              // 0.5 KB

    const bool bf = probe_is_bf16((const unsigned int*)emb_u);
    const unsigned char* mb = (const unsigned char*)mask;
    const int mm = (mb[1] == 0) ? 0 : ((mb[0] == 1) ? 1 : 2);

    if (bf) fused_body<true >(x_u, x_b, items, mask, mm, emb_u, emb_i, emb_b, A,
                              fc1_w, fc1_b, fc2_w, fc2_b, out_w, out_b, out, L,
                              it_s, hu_s, part, len_s, pfx_s, srow_s, sgrp_s,
                              x_s, h1_s, po_s);
    else    fused_body<false>(x_u, x_b, items, mask, mm, emb_u, emb_i, emb_b, A,
                              fc1_w, fc1_b, fc2_w, fc2_b, out_w, out_b, out, L,
                              it_s, hu_s, part, len_s, pfx_s, srow_s, sgrp_s,
                              x_s, h1_s, po_s);
}

extern "C" void kernel_launch(void* const* d_in, const int* in_sizes, int n_in,
                              void* d_out, int out_size, void* d_ws, size_t ws_size,
                              hipStream_t stream) {
    const int*  x_u   = (const int*)d_in[0];
    const int*  x_b   = (const int*)d_in[1];
    const int*  items = (const int*)d_in[2];
    const void* mask  = d_in[3];
    const void* emb_u = d_in[4];
    const void* emb_i = d_in[5];
    const void* emb_b = d_in[6];
    const void* A     = d_in[7];
    const void* fc1_w = d_in[8];
    const void* fc1_b = d_in[9];
    const void* fc2_w = d_in[10];
    const void* fc2_b = d_in[11];
    const void* out_w = d_in[12];
    const void* out_b = d_in[13];

    const int B = in_sizes[0];
    const int L = in_sizes[2] / B;

    fused_kernel<<<B / 16, 512, 0, stream>>>(x_u, x_b, items, mask,
                                             emb_u, emb_i, emb_b, A,
                                             fc1_w, fc1_b, fc2_w, fc2_b,
                                             out_w, out_b, d_out, L);
}